// Round 2
// baseline (1612.849 us; speedup 1.0000x reference)
//
#include <hip/hip_runtime.h>

// Problem constants (SumGCNEncoder): NU=NI=100000, DIN=DOUT=128, NS=5, E=500000
#define R_     100000   // rows per side (NU == NI)
#define NSUP   5
#define EDGES  500000
#define D_     128
#define ND     (NSUP * D_)   // 640
#define NEDGE_TOT (NSUP * EDGES)  // 2,500,000
#define NBUCKET   (NSUP * R_)     // 500,000

// scan config
#define SCAN_TILE 1024
#define SCAN_NB   ((NBUCKET + SCAN_TILE - 1) / SCAN_TILE)  // 489

using short8 = __attribute__((ext_vector_type(8))) short;
using f32x4  = __attribute__((ext_vector_type(4))) float;

static __device__ __forceinline__ unsigned short f2bf(float x) {
    unsigned u = __float_as_uint(x);
    unsigned r = (u + 0x7fffu + ((u >> 16) & 1u)) >> 16;   // RNE
    return (unsigned short)r;
}

// ---------------------------------------------------------------------------
// BT[o][k] = Wstack[k][o], k = i*128 + d, Wstack[k][o] = sum_{j<=i} w[d][o][j]
// weight layout fp32 [DIN][DOUT][NS] -> idx (d*128 + o)*5 + j.  BT: bf16 [128][640]
__global__ __launch_bounds__(256) void build_bt(const float* __restrict__ w,
                                                unsigned short* __restrict__ bt) {
    int t = blockIdx.x * 256 + threadIdx.x;
    if (t >= D_ * ND) return;
    int o = t / ND;
    int kk = t - o * ND;
    int i = kk >> 7;        // support
    int d = kk & 127;
    float s = 0.f;
    for (int j = 0; j <= i; j++) s += w[(d * D_ + o) * NSUP + j];
    bt[t] = f2bf(s);
}

// ---------------------------------------------------------------------------
// CSR build: count -> scan -> fill
__global__ __launch_bounds__(256) void count_k(const int* __restrict__ rows,
                                               int* __restrict__ counts) {
    int t = blockIdx.x * 256 + threadIdx.x;
    if (t >= NEDGE_TOT) return;
    int i = t / EDGES;
    atomicAdd(&counts[i * R_ + rows[t]], 1);
}

__global__ __launch_bounds__(256) void scan_pass1(const int* __restrict__ counts,
                                                  int* __restrict__ scanned,
                                                  int* __restrict__ partials) {
    __shared__ int sh[256];
    int blk = blockIdx.x, tid = threadIdx.x;
    int base = blk * SCAN_TILE + tid * 4;
    int v[4];
#pragma unroll
    for (int i = 0; i < 4; i++) {
        int idx = base + i;
        v[i] = (idx < NBUCKET) ? counts[idx] : 0;
    }
    int tsum = v[0] + v[1] + v[2] + v[3];
    sh[tid] = tsum;
    __syncthreads();
    for (int off = 1; off < 256; off <<= 1) {
        int t = (tid >= off) ? sh[tid - off] : 0;
        __syncthreads();
        sh[tid] += t;
        __syncthreads();
    }
    int run = sh[tid] - tsum;   // exclusive
    if (tid == 255) partials[blk] = sh[255];
#pragma unroll
    for (int i = 0; i < 4; i++) {
        int idx = base + i;
        if (idx < NBUCKET) scanned[idx] = run;
        run += v[i];
    }
}

__global__ __launch_bounds__(512) void scan_pass2(int* __restrict__ partials, int nb) {
    __shared__ int sh[512];
    int tid = threadIdx.x;
    int v = (tid < nb) ? partials[tid] : 0;
    sh[tid] = v;
    __syncthreads();
    for (int off = 1; off < 512; off <<= 1) {
        int t = (tid >= off) ? sh[tid - off] : 0;
        __syncthreads();
        sh[tid] += t;
        __syncthreads();
    }
    if (tid < nb) partials[tid] = sh[tid] - v;  // exclusive
}

__global__ __launch_bounds__(256) void scan_pass3(int* __restrict__ scanned,
                                                  const int* __restrict__ partials) {
    int blk = blockIdx.x, tid = threadIdx.x;
    int add = partials[blk];
    int base = blk * SCAN_TILE + tid * 4;
#pragma unroll
    for (int i = 0; i < 4; i++) {
        int idx = base + i;
        if (idx < NBUCKET) scanned[idx] += add;
    }
}

__global__ __launch_bounds__(256) void fill_k(const int* __restrict__ rows,
                                              const int* __restrict__ cols,
                                              const float* __restrict__ vals,
                                              int* __restrict__ cursor,
                                              int* __restrict__ pcol,
                                              float* __restrict__ pval) {
    int t = blockIdx.x * 256 + threadIdx.x;
    if (t >= NEDGE_TOT) return;
    int i = t / EDGES;
    int pos = atomicAdd(&cursor[i * R_ + rows[t]], 1);
    pcol[pos] = cols[t];
    pval[pos] = vals[t];
}

// ---------------------------------------------------------------------------
// Gather S[row, i*128 + :] = sum_e val_e * src[col_e, :]  (one wave per bucket)
// src: fp32 [R_,128]; S: bf16 [R_,640]. Lane handles 2 feature cols (float2).
__global__ __launch_bounds__(256) void gather_spmm(const int* __restrict__ counts,
                                                   const int* __restrict__ cursor,
                                                   const int* __restrict__ pcol,
                                                   const float* __restrict__ pval,
                                                   const float* __restrict__ src,
                                                   unsigned short* __restrict__ S) {
    int w = (blockIdx.x * 256 + threadIdx.x) >> 6;   // bucket id = i*R_ + row
    int lane = threadIdx.x & 63;
    if (w >= NBUCKET) return;
    int i = w / R_;
    int row = w - i * R_;
    int cnt = counts[w];
    int end = cursor[w];          // after fill, cursor = start + count
    int st = end - cnt;
    float a0 = 0.f, a1 = 0.f;
    for (int e = st; e < end; e++) {
        int c = pcol[e];
        float v = pval[e];
        float2 p = *(const float2*)(src + (size_t)c * D_ + lane * 2);
        a0 += v * p.x;
        a1 += v * p.y;
    }
    unsigned o = ((unsigned)f2bf(a1) << 16) | (unsigned)f2bf(a0);
    *(unsigned*)(S + (size_t)row * ND + i * D_ + lane * 2) = o;
}

// ---------------------------------------------------------------------------
// out[row, o] = relu( sum_k S[row,k] * BT[o,k] ), MFMA 16x16x32 bf16, K=640
// Wave = 16-row strip x all 128 output cols (8 n-tiles). out: fp32.
__global__ __launch_bounds__(256) void gemm_relu(const unsigned short* __restrict__ S,
                                                 const unsigned short* __restrict__ BT,
                                                 float* __restrict__ out) {
    int wid = threadIdx.x >> 6, lane = threadIdx.x & 63;
    int strip = blockIdx.x * 4 + wid;
    if (strip * 16 >= R_) return;
    int r = lane & 15, q = lane >> 4;

    f32x4 acc[8];
#pragma unroll
    for (int nt = 0; nt < 8; nt++) acc[nt] = (f32x4){0.f, 0.f, 0.f, 0.f};

    const unsigned short* aptr = S + (size_t)(strip * 16 + r) * ND + q * 8;
    for (int c = 0; c < 20; c++) {
        short8 a = *(const short8*)(aptr + c * 32);
#pragma unroll
        for (int nt = 0; nt < 8; nt++) {
            const unsigned short* bptr = BT + (size_t)(nt * 16 + r) * ND + q * 8 + c * 32;
            short8 b = *(const short8*)bptr;
            acc[nt] = __builtin_amdgcn_mfma_f32_16x16x32_bf16(a, b, acc[nt], 0, 0, 0);
        }
    }

    int base = strip * 16;
#pragma unroll
    for (int nt = 0; nt < 8; nt++) {
#pragma unroll
        for (int rr = 0; rr < 4; rr++) {
            int row = base + q * 4 + rr;
            int col = nt * 16 + r;
            float v = acc[nt][rr];
            out[(size_t)row * D_ + col] = v > 0.f ? v : 0.f;
        }
    }
}

// ---------------------------------------------------------------------------
extern "C" void kernel_launch(void* const* d_in, const int* in_sizes, int n_in,
                              void* d_out, int out_size, void* d_ws, size_t ws_size,
                              hipStream_t stream) {
    const float* user_in = (const float*)d_in[0];
    const float* item_in = (const float*)d_in[1];
    const float* weight  = (const float*)d_in[2];
    const int* u_rows = (const int*)d_in[3];
    const int* u_cols = (const int*)d_in[4];
    const float* u_vals = (const float*)d_in[5];
    const int* i_rows = (const int*)d_in[6];
    const int* i_cols = (const int*)d_in[7];
    const float* i_vals = (const float*)d_in[8];
    float* out = (float*)d_out;

    // workspace layout (bytes)
    char* ws = (char*)d_ws;
    unsigned short* S  = (unsigned short*)(ws);                       // 128,000,000 B
    unsigned short* BT = (unsigned short*)(ws + 128000000);           // 163,840 B
    int*   counts  = (int*)  (ws + 128163840);                        // 2,000,000 B
    int*   cursor  = (int*)  (ws + 130163840);                        // 2,000,000 B
    int*   partials= (int*)  (ws + 132163840);                        // 2,048 B
    int*   pcol    = (int*)  (ws + 132165888);                        // 10,000,000 B
    float* pval    = (float*)(ws + 142165888);                        // 10,000,000 B
    // total ~152.2 MB

    build_bt<<<(D_ * ND + 255) / 256, 256, 0, stream>>>(weight, BT);

    const int nb_edges = (NEDGE_TOT + 255) / 256;    // 9766
    const int nb_gath  = NBUCKET / 4;                // 125000 (4 waves/block)
    const int nb_gemm  = (R_ / 16 + 3) / 4;          // 1563

    for (int side = 0; side < 2; side++) {
        const int* rows = side ? i_rows : u_rows;
        const int* cols = side ? i_cols : u_cols;
        const float* vals = side ? i_vals : u_vals;
        const float* src  = side ? user_in : item_in;  // user_hidden gathers item features
        float* out_side = out + (size_t)side * R_ * D_;

        hipMemsetAsync(counts, 0, NBUCKET * sizeof(int), stream);
        count_k<<<nb_edges, 256, 0, stream>>>(rows, counts);
        scan_pass1<<<SCAN_NB, 256, 0, stream>>>(counts, cursor, partials);
        scan_pass2<<<1, 512, 0, stream>>>(partials, SCAN_NB);
        scan_pass3<<<SCAN_NB, 256, 0, stream>>>(cursor, partials);
        fill_k<<<nb_edges, 256, 0, stream>>>(rows, cols, vals, cursor, pcol, pval);
        gather_spmm<<<nb_gath, 256, 0, stream>>>(counts, cursor, pcol, pval, src, S);
        gemm_relu<<<nb_gemm, 256, 0, stream>>>(S, BT, out_side);
    }
}

// Round 3
// 1305.857 us; speedup vs baseline: 1.2351x; 1.2351x over previous
//
#include <hip/hip_runtime.h>

// SumGCNEncoder: NU=NI=100000, DIN=DOUT=128, NS=5, E=500000
#define R_     100000
#define NSUP   5
#define EDGES  500000
#define D_     128
#define ND     (NSUP * D_)          // 640
#define NEDGE_TOT (NSUP * EDGES)    // 2,500,000 (per side)
#define NBUCKET   (NSUP * R_)       // 500,000 (per side)
#define CHUNK  50000                // rows per gather/gemm chunk
#define SROWS  (CHUNK + 16)         // S buffer rows (pad for 32-row gemm waves)

#define SCAN_TILE 1024
#define SCAN_NB   ((NBUCKET + SCAN_TILE - 1) / SCAN_TILE)  // 489

using short8 = __attribute__((ext_vector_type(8))) short;
using f32x4  = __attribute__((ext_vector_type(4))) float;

static __device__ __forceinline__ float bf2f_lo(unsigned p) {
    return __uint_as_float(p << 16);
}
static __device__ __forceinline__ float bf2f_hi(unsigned p) {
    return __uint_as_float(p & 0xffff0000u);
}
static __device__ __forceinline__ unsigned short f2bf(float x) {
    unsigned u = __float_as_uint(x);
    return (unsigned short)((u + 0x7fffu + ((u >> 16) & 1u)) >> 16);  // RNE
}

// ---------------------------------------------------------------------------
// BT[o][k], k=i*128+d: cumulative weight sum, transposed. bf16 [128][640]
__global__ __launch_bounds__(256) void build_bt(const float* __restrict__ w,
                                                unsigned short* __restrict__ bt) {
    int t = blockIdx.x * 256 + threadIdx.x;
    if (t >= D_ * ND) return;
    int o = t / ND;
    int kk = t - o * ND;
    int i = kk >> 7, d = kk & 127;
    float s = 0.f;
    for (int j = 0; j <= i; j++) s += w[(d * D_ + o) * NSUP + j];
    bt[t] = f2bf(s);
}

// fp32 [R_,128] -> bf16 table. 4 elems/thread.
__global__ __launch_bounds__(256) void conv_src(const float* __restrict__ src,
                                                unsigned short* __restrict__ dst) {
    int t = blockIdx.x * 256 + threadIdx.x;
    if (t * 4 >= R_ * D_) return;
    float4 v = *(const float4*)(src + t * 4);
    ushort4 o;
    o.x = f2bf(v.x); o.y = f2bf(v.y); o.z = f2bf(v.z); o.w = f2bf(v.w);
    *(ushort4*)(dst + t * 4) = o;
}

// ---------------------------------------------------------------------------
// CSR build
__global__ __launch_bounds__(256) void count_k(const int* __restrict__ rows,
                                               int* __restrict__ counts) {
    int t = blockIdx.x * 256 + threadIdx.x;
    if (t >= NEDGE_TOT) return;
    int i = t / EDGES;
    atomicAdd(&counts[i * R_ + rows[t]], 1);
}

__global__ __launch_bounds__(256) void scan_pass1(const int* __restrict__ counts,
                                                  int* __restrict__ scanned,
                                                  int* __restrict__ partials) {
    __shared__ int sh[256];
    int blk = blockIdx.x, tid = threadIdx.x;
    int base = blk * SCAN_TILE + tid * 4;
    int v[4];
#pragma unroll
    for (int i = 0; i < 4; i++) {
        int idx = base + i;
        v[i] = (idx < NBUCKET) ? counts[idx] : 0;
    }
    int tsum = v[0] + v[1] + v[2] + v[3];
    sh[tid] = tsum;
    __syncthreads();
    for (int off = 1; off < 256; off <<= 1) {
        int t = (tid >= off) ? sh[tid - off] : 0;
        __syncthreads();
        sh[tid] += t;
        __syncthreads();
    }
    int run = sh[tid] - tsum;
    if (tid == 255) partials[blk] = sh[255];
#pragma unroll
    for (int i = 0; i < 4; i++) {
        int idx = base + i;
        if (idx < NBUCKET) scanned[idx] = run;
        run += v[i];
    }
}

__global__ __launch_bounds__(512) void scan_pass2(int* __restrict__ partials, int nb) {
    __shared__ int sh[512];
    int tid = threadIdx.x;
    int v = (tid < nb) ? partials[tid] : 0;
    sh[tid] = v;
    __syncthreads();
    for (int off = 1; off < 512; off <<= 1) {
        int t = (tid >= off) ? sh[tid - off] : 0;
        __syncthreads();
        sh[tid] += t;
        __syncthreads();
    }
    if (tid < nb) partials[tid] = sh[tid] - v;
}

__global__ __launch_bounds__(256) void scan_pass3(int* __restrict__ scanned,
                                                  const int* __restrict__ partials) {
    int blk = blockIdx.x, tid = threadIdx.x;
    int add = partials[blk];
    int base = blk * SCAN_TILE + tid * 4;
#pragma unroll
    for (int i = 0; i < 4; i++) {
        int idx = base + i;
        if (idx < NBUCKET) scanned[idx] += add;
    }
}

// pack (col, val) into one uint2 per edge
__global__ __launch_bounds__(256) void fill_k(const int* __restrict__ rows,
                                              const int* __restrict__ cols,
                                              const float* __restrict__ vals,
                                              int* __restrict__ cursor,
                                              uint2* __restrict__ pedge) {
    int t = blockIdx.x * 256 + threadIdx.x;
    if (t >= NEDGE_TOT) return;
    int i = t / EDGES;
    int pos = atomicAdd(&cursor[i * R_ + rows[t]], 1);
    uint2 e;
    e.x = (unsigned)cols[t];
    e.y = __float_as_uint(vals[t]);
    pedge[pos] = e;
}

// ---------------------------------------------------------------------------
// One wave per bucket (i,row) within the chunk. srcbf: bf16 [R_,128].
// S: bf16 [SROWS,640]. Lane = 2 feature cols (4B load). Unroll-4 for MLP.
__global__ __launch_bounds__(256) void gather_spmm(const int* __restrict__ counts,
                                                   const int* __restrict__ cursor,
                                                   const uint2* __restrict__ pedge,
                                                   const unsigned short* __restrict__ srcbf,
                                                   unsigned short* __restrict__ S,
                                                   int row0, int cr) {
    int l = (blockIdx.x * 256 + threadIdx.x) >> 6;   // local bucket
    int lane = threadIdx.x & 63;
    if (l >= NSUP * cr) return;
    int i = l / cr;
    int rl = l - i * cr;                 // local row
    int w = i * R_ + row0 + rl;          // global bucket
    int cnt = counts[w];
    int end = cursor[w];                 // start + count after fill
    int st  = end - cnt;

    float a0 = 0.f, a1 = 0.f;
    int e = st;
    int n4 = st + ((end - st) & ~3);
    for (; e < n4; e += 4) {
        uint2 E0 = pedge[e], E1 = pedge[e + 1], E2 = pedge[e + 2], E3 = pedge[e + 3];
        unsigned p0 = *(const unsigned*)(srcbf + (size_t)E0.x * D_ + lane * 2);
        unsigned p1 = *(const unsigned*)(srcbf + (size_t)E1.x * D_ + lane * 2);
        unsigned p2 = *(const unsigned*)(srcbf + (size_t)E2.x * D_ + lane * 2);
        unsigned p3 = *(const unsigned*)(srcbf + (size_t)E3.x * D_ + lane * 2);
        float v0 = __uint_as_float(E0.y), v1 = __uint_as_float(E1.y);
        float v2 = __uint_as_float(E2.y), v3 = __uint_as_float(E3.y);
        a0 += v0 * bf2f_lo(p0); a1 += v0 * bf2f_hi(p0);
        a0 += v1 * bf2f_lo(p1); a1 += v1 * bf2f_hi(p1);
        a0 += v2 * bf2f_lo(p2); a1 += v2 * bf2f_hi(p2);
        a0 += v3 * bf2f_lo(p3); a1 += v3 * bf2f_hi(p3);
    }
    for (; e < end; e++) {
        uint2 E = pedge[e];
        unsigned p = *(const unsigned*)(srcbf + (size_t)E.x * D_ + lane * 2);
        float v = __uint_as_float(E.y);
        a0 += v * bf2f_lo(p); a1 += v * bf2f_hi(p);
    }
    unsigned o = ((unsigned)f2bf(a1) << 16) | (unsigned)f2bf(a0);
    *(unsigned*)(S + (size_t)rl * ND + i * D_ + lane * 2) = o;
}

// ---------------------------------------------------------------------------
// out[row0+l, o] = relu(sum_k S[l,k]*BT[o,k]); 32 rows/wave, MFMA 16x16x32.
__global__ __launch_bounds__(256) void gemm_relu(const unsigned short* __restrict__ S,
                                                 const unsigned short* __restrict__ BT,
                                                 float* __restrict__ out,
                                                 int row0, int cr) {
    int wid = threadIdx.x >> 6, lane = threadIdx.x & 63;
    int wv = blockIdx.x * 4 + wid;
    int l0 = wv * 32;
    if (l0 >= cr) return;
    int r = lane & 15, q = lane >> 4;

    f32x4 acc0[8], acc1[8];
#pragma unroll
    for (int nt = 0; nt < 8; nt++) {
        acc0[nt] = (f32x4){0.f, 0.f, 0.f, 0.f};
        acc1[nt] = (f32x4){0.f, 0.f, 0.f, 0.f};
    }

    const unsigned short* a0p = S + (size_t)(l0 + r) * ND + q * 8;
    const unsigned short* a1p = S + (size_t)(l0 + 16 + r) * ND + q * 8;
    for (int c = 0; c < 20; c++) {
        short8 a0 = *(const short8*)(a0p + c * 32);
        short8 a1 = *(const short8*)(a1p + c * 32);
#pragma unroll
        for (int nt = 0; nt < 8; nt++) {
            short8 b = *(const short8*)(BT + (size_t)(nt * 16 + r) * ND + q * 8 + c * 32);
            acc0[nt] = __builtin_amdgcn_mfma_f32_16x16x32_bf16(a0, b, acc0[nt], 0, 0, 0);
            acc1[nt] = __builtin_amdgcn_mfma_f32_16x16x32_bf16(a1, b, acc1[nt], 0, 0, 0);
        }
    }

#pragma unroll
    for (int nt = 0; nt < 8; nt++) {
#pragma unroll
        for (int rr = 0; rr < 4; rr++) {
            int col = nt * 16 + r;
            int l = l0 + q * 4 + rr;
            if (l < cr) {
                float v = acc0[nt][rr];
                out[(size_t)(row0 + l) * D_ + col] = v > 0.f ? v : 0.f;
            }
            l += 16;
            if (l < cr) {
                float v = acc1[nt][rr];
                out[(size_t)(row0 + l) * D_ + col] = v > 0.f ? v : 0.f;
            }
        }
    }
}

// ---------------------------------------------------------------------------
extern "C" void kernel_launch(void* const* d_in, const int* in_sizes, int n_in,
                              void* d_out, int out_size, void* d_ws, size_t ws_size,
                              hipStream_t stream) {
    const float* user_in = (const float*)d_in[0];
    const float* item_in = (const float*)d_in[1];
    const float* weight  = (const float*)d_in[2];
    const int* u_rows = (const int*)d_in[3];
    const int* u_cols = (const int*)d_in[4];
    const float* u_vals = (const float*)d_in[5];
    const int* i_rows = (const int*)d_in[6];
    const int* i_cols = (const int*)d_in[7];
    const float* i_vals = (const float*)d_in[8];
    float* out = (float*)d_out;

    // ws layout (bytes), total ~113.8 MB (R2's 152 MB footprint passed)
    char* ws = (char*)d_ws;
    unsigned short* S    = (unsigned short*)(ws);                 // SROWS*640*2 = 64,020,480
    unsigned short* BT   = (unsigned short*)(ws + 64020480);      // 163,840
    unsigned short* srcb = (unsigned short*)(ws + 64184320);      // 25,600,000
    int*   counts   = (int*)  (ws + 89784320);                    // 2,000,000
    int*   cursor   = (int*)  (ws + 91784320);                    // 2,000,000
    int*   partials = (int*)  (ws + 93784320);                    // 2,048
    uint2* pedge    = (uint2*)(ws + 93786368);                    // 20,000,000  -> ends 113,786,368

    build_bt<<<(D_ * ND + 255) / 256, 256, 0, stream>>>(weight, BT);

    const int nb_edges = (NEDGE_TOT + 255) / 256;        // 9766
    const int nb_conv  = (R_ * D_ / 4 + 255) / 256;      // 12500
    const int nb_gath  = (NSUP * CHUNK) / 4;             // 62500
    const int nb_gemm  = ((CHUNK + 31) / 32 + 3) / 4;    // 391

    for (int side = 0; side < 2; side++) {
        const int* rows = side ? i_rows : u_rows;
        const int* cols = side ? i_cols : u_cols;
        const float* vals = side ? i_vals : u_vals;
        const float* src  = side ? user_in : item_in;    // user_hidden gathers item feats
        float* out_side = out + (size_t)side * R_ * D_;

        hipMemsetAsync(counts, 0, NBUCKET * sizeof(int), stream);
        conv_src<<<nb_conv, 256, 0, stream>>>(src, srcb);
        count_k<<<nb_edges, 256, 0, stream>>>(rows, counts);
        scan_pass1<<<SCAN_NB, 256, 0, stream>>>(counts, cursor, partials);
        scan_pass2<<<1, 512, 0, stream>>>(partials, SCAN_NB);
        scan_pass3<<<SCAN_NB, 256, 0, stream>>>(cursor, partials);
        fill_k<<<nb_edges, 256, 0, stream>>>(rows, cols, vals, cursor, pedge);

        for (int ch = 0; ch < 2; ch++) {
            int row0 = ch * CHUNK;
            int cr = (row0 + CHUNK <= R_) ? CHUNK : (R_ - row0);
            gather_spmm<<<nb_gath, 256, 0, stream>>>(counts, cursor, pedge, srcb, S, row0, cr);
            gemm_relu<<<nb_gemm, 256, 0, stream>>>(S, BT, out_side, row0, cr);
        }
    }
}